// Round 11
// baseline (156.128 us; speedup 1.0000x reference)
//
#include <hip/hip_runtime.h>

typedef __attribute__((ext_vector_type(8))) short bf16x8;
typedef __attribute__((ext_vector_type(4))) float f32x4;

__device__ __forceinline__ unsigned short f2bf(float x) {
    unsigned int u = __float_as_uint(x);
    u += 0x7FFFu + ((u >> 16) & 1u);        // round-to-nearest-even
    return (unsigned short)(u >> 16);
}

// async global->LDS, 16B per lane; LDS dest = wave-uniform base + lane*16.
__device__ __forceinline__ void gl_lds16(const void* g, void* l) {
    __builtin_amdgcn_global_load_lds(
        (__attribute__((address_space(1))) void*)((void*)g),
        (__attribute__((address_space(3))) void*)l, 16, 0, 0);
}

// ---------------------------------------------------------------------------
// prep: WbT[n][k] = bf16(W[k][n]) via coalesced 32x32 LDS transpose. Grid 64.
// ---------------------------------------------------------------------------
__global__ __launch_bounds__(256) void prep(const float* __restrict__ W,
                                            short* __restrict__ WbT) {
    __shared__ float tile[32][33];
    const int t = threadIdx.x;
    const int bx = blockIdx.x & 7, by = blockIdx.x >> 3;
    const int r0 = by * 32, c0 = bx * 32;
    const int lr = t >> 5, lc = t & 31;
#pragma unroll
    for (int q = 0; q < 4; ++q)
        tile[q * 8 + lr][lc] = W[(r0 + q * 8 + lr) * 256 + c0 + lc];
    __syncthreads();
#pragma unroll
    for (int q = 0; q < 4; ++q)
        WbT[(c0 + q * 8 + lr) * 256 + r0 + lc] = (short)f2bf(tile[lc][q * 8 + lr]);
}

// ---------------------------------------------------------------------------
// wh_f12: 32 nodes/block (grid 512). B-frags reused across 2 m-frags.
// WhT[b][f][j] stored bf16-transposed; f1/f2 from fp32 accumulators.
// ---------------------------------------------------------------------------
__global__ __launch_bounds__(256, 4) void wh_f12(const float* __restrict__ h,
                                                 const short* __restrict__ WbT,
                                                 const float* __restrict__ a,
                                                 short* __restrict__ WhT,
                                                 float* __restrict__ f1,
                                                 float* __restrict__ f2) {
    __shared__ short hA[32][264];      // +8 pad -> 2-way bank aliasing (free)
    __shared__ float sp[2][4][32];
    const int t = threadIdx.x;
    const int wid = t >> 6, lane = t & 63;
    const int quad = lane >> 4, l15 = lane & 15;
    const int m0 = blockIdx.x * 32;

#pragma unroll
    for (int rr = 0; rr < 2; ++rr) {
        const int r = rr * 16 + (t >> 4), c0 = (t & 15) * 16;
        const float* hp = h + (size_t)(m0 + r) * 256 + c0;
        float4 v0 = *(const float4*)(hp + 0), v1 = *(const float4*)(hp + 4);
        float4 v2 = *(const float4*)(hp + 8), v3 = *(const float4*)(hp + 12);
        bf16x8 w0, w1;
        w0[0] = (short)f2bf(v0.x); w0[1] = (short)f2bf(v0.y);
        w0[2] = (short)f2bf(v0.z); w0[3] = (short)f2bf(v0.w);
        w0[4] = (short)f2bf(v1.x); w0[5] = (short)f2bf(v1.y);
        w0[6] = (short)f2bf(v1.z); w0[7] = (short)f2bf(v1.w);
        w1[0] = (short)f2bf(v2.x); w1[1] = (short)f2bf(v2.y);
        w1[2] = (short)f2bf(v2.z); w1[3] = (short)f2bf(v2.w);
        w1[4] = (short)f2bf(v3.x); w1[5] = (short)f2bf(v3.y);
        w1[6] = (short)f2bf(v3.z); w1[7] = (short)f2bf(v3.w);
        *(bf16x8*)&hA[r][c0] = w0;
        *(bf16x8*)&hA[r][c0 + 8] = w1;
    }
    __syncthreads();

    f32x4 acc[2][4] = {};
#pragma unroll
    for (int kt = 0; kt < 8; ++kt) {
        const int k0 = kt * 32;
        bf16x8 bv[4];
#pragma unroll
        for (int ft = 0; ft < 4; ++ft)
            bv[ft] = *(const bf16x8*)(WbT + (size_t)(wid * 64 + ft * 16 + l15) * 256 + k0 + quad * 8);
        bf16x8 a0 = *(const bf16x8*)&hA[l15][k0 + quad * 8];
        bf16x8 a1 = *(const bf16x8*)&hA[16 + l15][k0 + quad * 8];
#pragma unroll
        for (int ft = 0; ft < 4; ++ft) {
            acc[0][ft] = __builtin_amdgcn_mfma_f32_16x16x32_bf16(a0, bv[ft], acc[0][ft], 0, 0, 0);
            acc[1][ft] = __builtin_amdgcn_mfma_f32_16x16x32_bf16(a1, bv[ft], acc[1][ft], 0, 0, 0);
        }
    }

    const int b = m0 >> 10;
#pragma unroll
    for (int mf = 0; mf < 2; ++mf) {
        const int il0 = (m0 & 1023) + mf * 16 + quad * 4;
#pragma unroll
        for (int ft = 0; ft < 4; ++ft) {
            const int f = wid * 64 + ft * 16 + l15;
            ushort4 pk;
            pk.x = f2bf(acc[mf][ft][0]);
            pk.y = f2bf(acc[mf][ft][1]);
            pk.z = f2bf(acc[mf][ft][2]);
            pk.w = f2bf(acc[mf][ft][3]);
            *(ushort4*)(WhT + ((size_t)b << 18) + (size_t)f * 1024 + il0) = pk;
        }
    }

    float a1v[4], a2v[4];
#pragma unroll
    for (int ft = 0; ft < 4; ++ft) {
        a1v[ft] = a[wid * 64 + ft * 16 + l15];
        a2v[ft] = a[256 + wid * 64 + ft * 16 + l15];
    }
    float p1[2][4] = {}, p2[2][4] = {};
#pragma unroll
    for (int mf = 0; mf < 2; ++mf)
#pragma unroll
        for (int ft = 0; ft < 4; ++ft)
#pragma unroll
            for (int r = 0; r < 4; ++r) {
                p1[mf][r] += acc[mf][ft][r] * a1v[ft];
                p2[mf][r] += acc[mf][ft][r] * a2v[ft];
            }
#pragma unroll
    for (int off = 1; off < 16; off <<= 1)
#pragma unroll
        for (int mf = 0; mf < 2; ++mf)
#pragma unroll
            for (int r = 0; r < 4; ++r) {
                p1[mf][r] += __shfl_xor(p1[mf][r], off);
                p2[mf][r] += __shfl_xor(p2[mf][r], off);
            }
    if (l15 == 0)
#pragma unroll
        for (int mf = 0; mf < 2; ++mf)
#pragma unroll
            for (int r = 0; r < 4; ++r) {
                sp[0][wid][mf * 16 + quad * 4 + r] = p1[mf][r];
                sp[1][wid][mf * 16 + quad * 4 + r] = p2[mf][r];
            }
    __syncthreads();
    if (t < 32) {
        f1[m0 + t] = sp[0][0][t] + sp[0][1][t] + sp[0][2][t] + sp[0][3][t];
        f2[m0 + t] = sp[1][0][t] + sp[1][1][t] + sp[1][2][t] + sp[1][3][t];
    }
}

// ---------------------------------------------------------------------------
// stats: wave per row, coalesced. One streaming pass over adj; emits
// bm[row][128] adjacency bitmask (bit j -> byte j/8, bit j%8) and
// msc[row] = (f1, m, 1/l, 0). No P materialization.
// ---------------------------------------------------------------------------
__global__ __launch_bounds__(256) void stats(const int* __restrict__ adj,
                                             const float* __restrict__ f1g,
                                             const float* __restrict__ f2g,
                                             unsigned char* __restrict__ bm,
                                             float4* __restrict__ msc) {
    const int wid = threadIdx.x >> 6, lane = threadIdx.x & 63;
    const int gid = blockIdx.x * 4 + wid;          // row 0..16383
    const int b = gid >> 10;
    const int* arow = adj + (size_t)gid * 1024;
    const float* f2b = f2g + (b << 10);
    const float f1r = f1g[gid];

    float e[16];
    unsigned int nib[4];
#pragma unroll
    for (int c = 0; c < 4; ++c) {
        int4 av = *(const int4*)(arow + lane * 4 + c * 256);
        float4 fv = *(const float4*)(f2b + lane * 4 + c * 256);
        float x0 = f1r + fv.x, x1 = f1r + fv.y, x2 = f1r + fv.z, x3 = f1r + fv.w;
        e[c * 4 + 0] = av.x ? fmaxf(x0, 0.2f * x0) : -3.0e38f;
        e[c * 4 + 1] = av.y ? fmaxf(x1, 0.2f * x1) : -3.0e38f;
        e[c * 4 + 2] = av.z ? fmaxf(x2, 0.2f * x2) : -3.0e38f;
        e[c * 4 + 3] = av.w ? fmaxf(x3, 0.2f * x3) : -3.0e38f;
        nib[c] = (av.x ? 1u : 0u) | (av.y ? 2u : 0u) | (av.z ? 4u : 0u) | (av.w ? 8u : 0u);
    }
    float m = e[0];
#pragma unroll
    for (int q = 1; q < 16; ++q) m = fmaxf(m, e[q]);
#pragma unroll
    for (int off = 32; off; off >>= 1) m = fmaxf(m, __shfl_xor(m, off));

    float l = 0.f;
#pragma unroll
    for (int q = 0; q < 16; ++q) l += __expf(e[q] - m);
#pragma unroll
    for (int off = 32; off; off >>= 1) l += __shfl_xor(l, off);

    // byte B = 32c + k holds j = 8B..8B+7: low nibble lane 2k, high lane 2k+1
#pragma unroll
    for (int c = 0; c < 4; ++c) {
        unsigned int other = __shfl_xor((int)nib[c], 1);
        if (!(lane & 1))
            bm[(size_t)gid * 128 + c * 32 + (lane >> 1)] =
                (unsigned char)(nib[c] | (other << 4));
    }
    if (lane == 0) msc[gid] = make_float4(f1r, m, 1.0f / l, 0.0f);
}

// ---------------------------------------------------------------------------
// agg: out[b] = P[b] @ WhT[b]^T with P recomputed in-register from
// bitmask + (f1,m,1/l) + f2 during A-tile staging (same LDS addresses the
// old gl_lds staging used -> conflict-free writes, frag reads unchanged).
// Block tile 64m x 128n, BK=128, 8 K-iters; B staged via gl_lds (its ~900cyc
// flight now overlaps the ~400cyc p-compute). 52 KB LDS, 2 blocks/CU.
// ---------------------------------------------------------------------------
__global__ __launch_bounds__(256, 2) void agg(const unsigned char* __restrict__ bm,
                                              const float4* __restrict__ msc,
                                              const float* __restrict__ f2g,
                                              const short* __restrict__ WhT,
                                              float* __restrict__ out) {
    __shared__ short As[64 * 128];    // 16 KB
    __shared__ short Bs[128 * 128];   // 32 KB
    __shared__ float sf2[1024];       // 4 KB

    const int t = threadIdx.x;
    const int wid = t >> 6, lane = t & 63;
    const int quad = lane >> 4, l15 = lane & 15;

    // XCD-aware decode: b = (id&7) + 8*(rest&1), n = (rest>>1)&1, m = rest>>2
    const int id = blockIdx.x;
    const int rest = id >> 3;
    const int b = (id & 7) + 8 * (rest & 1);
    const int n0 = ((rest >> 1) & 1) * 128;
    const int m0 = (rest >> 2) * 64;

    const short* Wb = WhT + ((size_t)b << 18);

    // B staging (unchanged from R10): thread t -> rows rt+16q, slot sl
    const int rt = t >> 4, sl = t & 15;
    const int w = (sl & 8) | ((sl & 7) ^ (rt & 7));     // global chunk index
    const int wA = w * 8;                                // short offset

    const short* gB[8];
    short* lB[8];
#pragma unroll
    for (int q = 0; q < 8; ++q) {
        gB[q] = Wb + (size_t)(n0 + rt + 16 * q) * 1024 + wA;
        lB[q] = Bs + t * 8 + q * 2048;
    }

    // per-thread row constants for A rows rt+16q
    float4 rc[4];
#pragma unroll
    for (int q = 0; q < 4; ++q)
        rc[q] = msc[(b << 10) + m0 + rt + 16 * q];
    const unsigned char* bmb = bm + (size_t)((b << 10) + m0 + rt) * 128;

    // f2 for this batch into LDS
    *(float4*)&sf2[t * 4] = *(const float4*)&f2g[(b << 10) + t * 4];
    __syncthreads();

    const int mh = (wid & 1) * 32;      // wave m-half
    const int nq = (wid >> 1) * 64;     // wave n-half

    f32x4 acc[2][4] = {};

    for (int it = 0; it < 8; ++it) {
        const int k0 = it * 128;
#pragma unroll
        for (int q = 0; q < 8; ++q) gl_lds16(gB[q] + k0, lB[q]);

        // ---- recompute A tile (p values) for rows rt+16q, j = k0+w*8..+8
        unsigned int bits[4];
#pragma unroll
        for (int q = 0; q < 4; ++q)
            bits[q] = bmb[(size_t)q * 16 * 128 + it * 16 + w];
        float4 fa = *(const float4*)&sf2[k0 + w * 8];
        float4 fb = *(const float4*)&sf2[k0 + w * 8 + 4];
        float f2v[8] = {fa.x, fa.y, fa.z, fa.w, fb.x, fb.y, fb.z, fb.w};
#pragma unroll
        for (int q = 0; q < 4; ++q) {
            bf16x8 pv;
#pragma unroll
            for (int jj = 0; jj < 8; ++jj) {
                float x = rc[q].x + f2v[jj];
                float ee = fmaxf(x, 0.2f * x);
                float p = __expf(ee - rc[q].y) * rc[q].z;
                pv[jj] = ((bits[q] >> jj) & 1u) ? (short)f2bf(p) : (short)0;
            }
            *(bf16x8*)(As + t * 8 + q * 2048) = pv;
        }
        __syncthreads();   // As writes + Bs gl_lds complete

#pragma unroll
        for (int kt = 0; kt < 4; ++kt) {
            const int wk = kt * 4 + quad;
            bf16x8 av[2], bv[4];
#pragma unroll
            for (int mf = 0; mf < 2; ++mf) {
                const int r = mh + mf * 16 + l15;
                const int s = (wk & 8) | ((wk & 7) ^ (r & 7));
                av[mf] = *(const bf16x8*)(As + r * 128 + s * 8);
            }
#pragma unroll
            for (int nf = 0; nf < 4; ++nf) {
                const int r = nq + nf * 16 + l15;
                const int s = (wk & 8) | ((wk & 7) ^ (r & 7));
                bv[nf] = *(const bf16x8*)(Bs + r * 128 + s * 8);
            }
#pragma unroll
            for (int mf = 0; mf < 2; ++mf)
#pragma unroll
                for (int nf = 0; nf < 4; ++nf)
                    acc[mf][nf] = __builtin_amdgcn_mfma_f32_16x16x32_bf16(av[mf], bv[nf], acc[mf][nf], 0, 0, 0);
        }
        __syncthreads();   // frag reads done before next iter overwrites
    }

    // epilogue: C row = quad*4+reg, col = l15
#pragma unroll
    for (int mf = 0; mf < 2; ++mf) {
        const int i = m0 + mh + mf * 16 + quad * 4;
#pragma unroll
        for (int nf = 0; nf < 4; ++nf) {
            float* op = out + (size_t)((b << 10) + i) * 256 + n0 + nq + nf * 16 + l15;
            op[0]   = acc[mf][nf][0];
            op[256] = acc[mf][nf][1];
            op[512] = acc[mf][nf][2];
            op[768] = acc[mf][nf][3];
        }
    }
}

// ---------------------------------------------------------------------------
extern "C" void kernel_launch(void* const* d_in, const int* in_sizes, int n_in,
                              void* d_out, int out_size, void* d_ws, size_t ws_size,
                              hipStream_t stream) {
    const float* h   = (const float*)d_in[0];
    const int*   adj = (const int*)d_in[1];
    const float* W   = (const float*)d_in[2];
    const float* a   = (const float*)d_in[3];
    float* out = (float*)d_out;

    short* WbT = (short*)d_ws;                         // 128 KB
    float* f1  = (float*)(WbT + 65536);                // 64 KB
    float* f2  = f1 + 16384;                           // 64 KB
    short* WhT = (short*)(f2 + 16384);                 // 8 MB
    float4* msc = (float4*)(WhT + 16 * 256 * 1024);    // 256 KB
    unsigned char* bmsk = (unsigned char*)(msc + 16384); // 2 MB

    prep<<<64, 256, 0, stream>>>(W, WbT);
    wh_f12<<<512, 256, 0, stream>>>(h, WbT, a, WhT, f1, f2);
    stats<<<4096, 256, 0, stream>>>(adj, f1, f2, bmsk, msc);
    agg<<<512, 256, 0, stream>>>(bmsk, msc, f2, WhT, out);
}

// Round 12
// 152.389 us; speedup vs baseline: 1.0245x; 1.0245x over previous
//
#include <hip/hip_runtime.h>

typedef __attribute__((ext_vector_type(8))) short bf16x8;
typedef __attribute__((ext_vector_type(4))) float f32x4;

__device__ __forceinline__ unsigned short f2bf(float x) {
    unsigned int u = __float_as_uint(x);
    u += 0x7FFFu + ((u >> 16) & 1u);        // round-to-nearest-even
    return (unsigned short)(u >> 16);
}

// async global->LDS, 16B per lane; LDS dest = wave-uniform base + lane*16.
__device__ __forceinline__ void gl_lds16(const void* g, void* l) {
    __builtin_amdgcn_global_load_lds(
        (__attribute__((address_space(1))) void*)((void*)g),
        (__attribute__((address_space(3))) void*)l, 16, 0, 0);
}

// ---------------------------------------------------------------------------
// prep: WbT[n][k] = bf16(W[k][n]) via coalesced 32x32 LDS transpose. Grid 64.
// ---------------------------------------------------------------------------
__global__ __launch_bounds__(256) void prep(const float* __restrict__ W,
                                            short* __restrict__ WbT) {
    __shared__ float tile[32][33];
    const int t = threadIdx.x;
    const int bx = blockIdx.x & 7, by = blockIdx.x >> 3;
    const int r0 = by * 32, c0 = bx * 32;
    const int lr = t >> 5, lc = t & 31;
#pragma unroll
    for (int q = 0; q < 4; ++q)
        tile[q * 8 + lr][lc] = W[(r0 + q * 8 + lr) * 256 + c0 + lc];
    __syncthreads();
#pragma unroll
    for (int q = 0; q < 4; ++q)
        WbT[(c0 + q * 8 + lr) * 256 + r0 + lc] = (short)f2bf(tile[lc][q * 8 + lr]);
}

// ---------------------------------------------------------------------------
// wh_f12: 32 nodes/block (grid 512). B-frags reused across 2 m-frags.
// WhT[b][f][j] stored bf16-transposed; f1/f2 from fp32 accumulators.
// ---------------------------------------------------------------------------
__global__ __launch_bounds__(256, 4) void wh_f12(const float* __restrict__ h,
                                                 const short* __restrict__ WbT,
                                                 const float* __restrict__ a,
                                                 short* __restrict__ WhT,
                                                 float* __restrict__ f1,
                                                 float* __restrict__ f2) {
    __shared__ short hA[32][264];      // +8 pad -> 2-way bank aliasing (free)
    __shared__ float sp[2][4][32];
    const int t = threadIdx.x;
    const int wid = t >> 6, lane = t & 63;
    const int quad = lane >> 4, l15 = lane & 15;
    const int m0 = blockIdx.x * 32;

    // --- stage h-tile (2 rows per 16-thread group; 64 B contiguous/thread)
#pragma unroll
    for (int rr = 0; rr < 2; ++rr) {
        const int r = rr * 16 + (t >> 4), c0 = (t & 15) * 16;
        const float* hp = h + (size_t)(m0 + r) * 256 + c0;
        float4 v0 = *(const float4*)(hp + 0), v1 = *(const float4*)(hp + 4);
        float4 v2 = *(const float4*)(hp + 8), v3 = *(const float4*)(hp + 12);
        bf16x8 w0, w1;
        w0[0] = (short)f2bf(v0.x); w0[1] = (short)f2bf(v0.y);
        w0[2] = (short)f2bf(v0.z); w0[3] = (short)f2bf(v0.w);
        w0[4] = (short)f2bf(v1.x); w0[5] = (short)f2bf(v1.y);
        w0[6] = (short)f2bf(v1.z); w0[7] = (short)f2bf(v1.w);
        w1[0] = (short)f2bf(v2.x); w1[1] = (short)f2bf(v2.y);
        w1[2] = (short)f2bf(v2.z); w1[3] = (short)f2bf(v2.w);
        w1[4] = (short)f2bf(v3.x); w1[5] = (short)f2bf(v3.y);
        w1[6] = (short)f2bf(v3.z); w1[7] = (short)f2bf(v3.w);
        *(bf16x8*)&hA[r][c0] = w0;
        *(bf16x8*)&hA[r][c0 + 8] = w1;
    }
    __syncthreads();

    f32x4 acc[2][4] = {};
#pragma unroll
    for (int kt = 0; kt < 8; ++kt) {
        const int k0 = kt * 32;
        bf16x8 bv[4];
#pragma unroll
        for (int ft = 0; ft < 4; ++ft)
            bv[ft] = *(const bf16x8*)(WbT + (size_t)(wid * 64 + ft * 16 + l15) * 256 + k0 + quad * 8);
        bf16x8 a0 = *(const bf16x8*)&hA[l15][k0 + quad * 8];
        bf16x8 a1 = *(const bf16x8*)&hA[16 + l15][k0 + quad * 8];
#pragma unroll
        for (int ft = 0; ft < 4; ++ft) {
            acc[0][ft] = __builtin_amdgcn_mfma_f32_16x16x32_bf16(a0, bv[ft], acc[0][ft], 0, 0, 0);
            acc[1][ft] = __builtin_amdgcn_mfma_f32_16x16x32_bf16(a1, bv[ft], acc[1][ft], 0, 0, 0);
        }
    }

    // --- WhT store (C row = quad*4+reg, col f = wid*64+ft*16+l15)
    const int b = m0 >> 10;
#pragma unroll
    for (int mf = 0; mf < 2; ++mf) {
        const int il0 = (m0 & 1023) + mf * 16 + quad * 4;
#pragma unroll
        for (int ft = 0; ft < 4; ++ft) {
            const int f = wid * 64 + ft * 16 + l15;
            ushort4 pk;
            pk.x = f2bf(acc[mf][ft][0]);
            pk.y = f2bf(acc[mf][ft][1]);
            pk.z = f2bf(acc[mf][ft][2]);
            pk.w = f2bf(acc[mf][ft][3]);
            *(ushort4*)(WhT + ((size_t)b << 18) + (size_t)f * 1024 + il0) = pk;
        }
    }

    // --- f1/f2 from fp32 acc: dot with a1/a2 over this wave's 64-f slice
    float a1v[4], a2v[4];
#pragma unroll
    for (int ft = 0; ft < 4; ++ft) {
        a1v[ft] = a[wid * 64 + ft * 16 + l15];
        a2v[ft] = a[256 + wid * 64 + ft * 16 + l15];
    }
    float p1[2][4] = {}, p2[2][4] = {};
#pragma unroll
    for (int mf = 0; mf < 2; ++mf)
#pragma unroll
        for (int ft = 0; ft < 4; ++ft)
#pragma unroll
            for (int r = 0; r < 4; ++r) {
                p1[mf][r] += acc[mf][ft][r] * a1v[ft];
                p2[mf][r] += acc[mf][ft][r] * a2v[ft];
            }
#pragma unroll
    for (int off = 1; off < 16; off <<= 1)
#pragma unroll
        for (int mf = 0; mf < 2; ++mf)
#pragma unroll
            for (int r = 0; r < 4; ++r) {
                p1[mf][r] += __shfl_xor(p1[mf][r], off);
                p2[mf][r] += __shfl_xor(p2[mf][r], off);
            }
    if (l15 == 0)
#pragma unroll
        for (int mf = 0; mf < 2; ++mf)
#pragma unroll
            for (int r = 0; r < 4; ++r) {
                sp[0][wid][mf * 16 + quad * 4 + r] = p1[mf][r];
                sp[1][wid][mf * 16 + quad * 4 + r] = p2[mf][r];
            }
    __syncthreads();
    if (t < 32) {
        f1[m0 + t] = sp[0][0][t] + sp[0][1][t] + sp[0][2][t] + sp[0][3][t];
        f2[m0 + t] = sp[1][0][t] + sp[1][1][t] + sp[1][2][t] + sp[1][3][t];
    }
}

// ---------------------------------------------------------------------------
// stats_p: wave per row, coalesced (every load instr covers 1 KB contiguous).
// One streaming pass over adj; writes normalized P = bf16(exp(e-m)/l).
// ---------------------------------------------------------------------------
__global__ __launch_bounds__(256) void stats_p(const int* __restrict__ adj,
                                               const float* __restrict__ f1g,
                                               const float* __restrict__ f2g,
                                               short* __restrict__ P) {
    const int wid = threadIdx.x >> 6, lane = threadIdx.x & 63;
    const int gid = blockIdx.x * 4 + wid;          // row 0..16383
    const int b = gid >> 10;
    const int* arow = adj + (size_t)gid * 1024;
    const float* f2b = f2g + (b << 10);
    const float f1r = f1g[gid];

    float e[16];
#pragma unroll
    for (int c = 0; c < 4; ++c) {
        int4 av = *(const int4*)(arow + lane * 4 + c * 256);
        float4 fv = *(const float4*)(f2b + lane * 4 + c * 256);
        float x0 = f1r + fv.x, x1 = f1r + fv.y, x2 = f1r + fv.z, x3 = f1r + fv.w;
        e[c * 4 + 0] = av.x ? fmaxf(x0, 0.2f * x0) : -3.0e38f;
        e[c * 4 + 1] = av.y ? fmaxf(x1, 0.2f * x1) : -3.0e38f;
        e[c * 4 + 2] = av.z ? fmaxf(x2, 0.2f * x2) : -3.0e38f;
        e[c * 4 + 3] = av.w ? fmaxf(x3, 0.2f * x3) : -3.0e38f;
    }
    float m = e[0];
#pragma unroll
    for (int q = 1; q < 16; ++q) m = fmaxf(m, e[q]);
#pragma unroll
    for (int off = 32; off; off >>= 1) m = fmaxf(m, __shfl_xor(m, off));

    float p[16];
    float l = 0.f;
#pragma unroll
    for (int q = 0; q < 16; ++q) { p[q] = __expf(e[q] - m); l += p[q]; }
#pragma unroll
    for (int off = 32; off; off >>= 1) l += __shfl_xor(l, off);
    const float invl = 1.0f / l;

    short* prow = P + (size_t)gid * 1024;
#pragma unroll
    for (int c = 0; c < 4; ++c) {
        ushort4 pk;
        pk.x = f2bf(p[c * 4 + 0] * invl);
        pk.y = f2bf(p[c * 4 + 1] * invl);
        pk.z = f2bf(p[c * 4 + 2] * invl);
        pk.w = f2bf(p[c * 4 + 3] * invl);
        *(ushort4*)(prow + lane * 4 + c * 256) = pk;
    }
}

// ---------------------------------------------------------------------------
// agg: out[b] = P[b] @ WhT[b]^T. Block tile 64m x 128n, BK=64; wave tile
// 32m x 64n (12 ds_read_b128 per 16 MFMA). XOR chunk swizzle in LDS (2-way
// bank aliasing = free, global reads stay 128B-coalesced). 1D grid 512 with
// XCD decode (b % 8 == blockIdx % 8): both batches' WhT (1 MB) pin in the
// local 4 MB L2; P n-pair reuse is L2-local. 2 blocks/CU, all co-resident.
// ---------------------------------------------------------------------------
__global__ __launch_bounds__(256, 4) void agg(const short* __restrict__ P,
                                              const short* __restrict__ WhT,
                                              float* __restrict__ out) {
    __shared__ short As[64 * 64];    // 8 KB
    __shared__ short Bs[128 * 64];   // 16 KB

    const int t = threadIdx.x;
    const int wid = t >> 6, lane = t & 63;
    const int quad = lane >> 4, l15 = lane & 15;

    // XCD-aware decode: xcd = id&7, b = xcd + 8*(rest&1), n = (rest>>1)&1, m = rest>>2
    const int id = blockIdx.x;
    const int xcd = id & 7, rest = id >> 3;
    const int b = xcd + 8 * (rest & 1);
    const int n0 = ((rest >> 1) & 1) * 128;
    const int m0 = (rest >> 2) * 64;

    const short* Pb = P + ((size_t)b << 20);
    const short* Wb = WhT + ((size_t)b << 18);

    // staging: LDS chunk c (16B) -> row c>>3, slot c&7; global chunk = slot ^ (row&7)
    const int rA = t >> 3, wA = (t & 7) ^ (rA & 7);          // A chunks c=t, t+256
    const short* gA0 = Pb + (size_t)(m0 + rA) * 1024 + wA * 8;
    const short* gA1 = Pb + (size_t)(m0 + 32 + rA) * 1024 + wA * 8;
    const short* gB0 = Wb + (size_t)(n0 + rA) * 1024 + wA * 8;        // B c=t..t+768
    const short* gB1 = Wb + (size_t)(n0 + 32 + rA) * 1024 + wA * 8;
    const short* gB2 = Wb + (size_t)(n0 + 64 + rA) * 1024 + wA * 8;
    const short* gB3 = Wb + (size_t)(n0 + 96 + rA) * 1024 + wA * 8;
    short* lA0 = As + t * 8;
    short* lA1 = As + 2048 + t * 8;
    short* lB0 = Bs + t * 8;
    short* lB1 = Bs + 2048 + t * 8;
    short* lB2 = Bs + 4096 + t * 8;
    short* lB3 = Bs + 6144 + t * 8;

    const int mh = (wid & 1) * 32;      // wave m-half
    const int nq = (wid >> 1) * 64;     // wave n-quarter

    f32x4 acc[2][4] = {};

    for (int k0 = 0; k0 < 1024; k0 += 64) {
        gl_lds16(gA0 + k0, lA0);
        gl_lds16(gA1 + k0, lA1);
        gl_lds16(gB0 + k0, lB0);
        gl_lds16(gB1 + k0, lB1);
        gl_lds16(gB2 + k0, lB2);
        gl_lds16(gB3 + k0, lB3);
        __syncthreads();

#pragma unroll
        for (int kt = 0; kt < 2; ++kt) {
            const int w = kt * 4 + quad;
            bf16x8 av[2], bv[4];
#pragma unroll
            for (int mf = 0; mf < 2; ++mf) {
                const int r = mh + mf * 16 + l15;
                av[mf] = *(const bf16x8*)(As + r * 64 + ((w ^ (r & 7)) * 8));
            }
#pragma unroll
            for (int nf = 0; nf < 4; ++nf) {
                const int r = nq + nf * 16 + l15;
                bv[nf] = *(const bf16x8*)(Bs + r * 64 + ((w ^ (r & 7)) * 8));
            }
#pragma unroll
            for (int mf = 0; mf < 2; ++mf)
#pragma unroll
                for (int nf = 0; nf < 4; ++nf)
                    acc[mf][nf] = __builtin_amdgcn_mfma_f32_16x16x32_bf16(av[mf], bv[nf], acc[mf][nf], 0, 0, 0);
        }
        __syncthreads();
    }

    // epilogue: C row = quad*4+reg, col = l15
#pragma unroll
    for (int mf = 0; mf < 2; ++mf) {
        const int i = m0 + mh + mf * 16 + quad * 4;
#pragma unroll
        for (int nf = 0; nf < 4; ++nf) {
            float* op = out + (size_t)((b << 10) + i) * 256 + n0 + nq + nf * 16 + l15;
            op[0]   = acc[mf][nf][0];
            op[256] = acc[mf][nf][1];
            op[512] = acc[mf][nf][2];
            op[768] = acc[mf][nf][3];
        }
    }
}

// ---------------------------------------------------------------------------
extern "C" void kernel_launch(void* const* d_in, const int* in_sizes, int n_in,
                              void* d_out, int out_size, void* d_ws, size_t ws_size,
                              hipStream_t stream) {
    const float* h   = (const float*)d_in[0];
    const int*   adj = (const int*)d_in[1];
    const float* W   = (const float*)d_in[2];
    const float* a   = (const float*)d_in[3];
    float* out = (float*)d_out;

    short* WbT = (short*)d_ws;                       // 128 KB
    float* f1  = (float*)(WbT + 65536);              // 64 KB
    float* f2  = f1 + 16384;                         // 64 KB
    short* WhT = (short*)(f2 + 16384);               // 8 MB
    short* P   = WhT + 16 * 256 * 1024;              // 32 MB

    prep<<<64, 256, 0, stream>>>(W, WbT);
    wh_f12<<<512, 256, 0, stream>>>(h, WbT, a, WhT, f1, f2);
    stats_p<<<4096, 256, 0, stream>>>(adj, f1, f2, P);
    agg<<<512, 256, 0, stream>>>(P, WhT, out);
}